// Round 7
// baseline (69.186 us; speedup 1.0000x reference)
//
#include <hip/hip_runtime.h>
#include <math.h>

// Problem constants (from reference)
#define B_    64
#define C_    8
#define T_    2048
#define K_    16
#define NF_   9
#define FEAT_ 144   // C_*NF_*2
#define MLP_  16
#define H1_   64
#define H2_   32
#define EFF_  60
#define W_    1988  // T_-EFF_
#define NWCH_ 8     // ceil(W_/256)
#define PI_F  3.14159265358979323846f

// Twiddles: angle(t) = 2*pi*t/16; f[n] = sum win[k]*exp(-i*2*pi*n*k/16)
constexpr float COS16[16] = {
   1.0f,  0.92387953251128674f,  0.70710678118654752f,  0.38268343236508977f,
   0.0f, -0.38268343236508977f, -0.70710678118654752f, -0.92387953251128674f,
  -1.0f, -0.92387953251128674f, -0.70710678118654752f, -0.38268343236508977f,
   0.0f,  0.38268343236508977f,  0.70710678118654752f,  0.92387953251128674f };
constexpr float SIN16F[16] = {
   0.0f,  0.38268343236508977f,  0.70710678118654752f,  0.92387953251128674f,
   1.0f,  0.92387953251128674f,  0.70710678118654752f,  0.38268343236508977f,
   0.0f, -0.38268343236508977f, -0.70710678118654752f, -0.92387953251128674f,
  -1.0f, -0.92387953251128674f, -0.70710678118654752f, -0.38268343236508977f };

// ---- fast device math (hw transcendentals) ----
__device__ __forceinline__ float fast_log1p(float s) {
  return __builtin_amdgcn_logf(1.0f + s) * 0.69314718055994531f;
}

__device__ __forceinline__ float atanpi_poly(float r) {
  const float s2 = r * r;
  float p = -0.0037310f;
  p = fmaf(p, s2,  0.0167600f);
  p = fmaf(p, s2, -0.0370617f);
  p = fmaf(p, s2,  0.0616068f);
  p = fmaf(p, s2, -0.10587734f);
  p = fmaf(p, s2,  0.31830265f);
  return r * p;
}

__device__ __forceinline__ float atan2pi_fast(float im, float re) {
  const float ax = fabsf(re), ay = fabsf(im);
  const float mx = fmaxf(ax, ay), mn = fminf(ax, ay);
  const float r = mn * __builtin_amdgcn_rcpf(fmaxf(mx, 1e-37f));
  float t = atanpi_poly(r);
  t = (ay > ax) ? 0.5f - t : t;
  t = (__float_as_uint(re) & 0x80000000u) ? 1.0f - t : t;  // signbit(re), handles -0
  return copysignf(t, im);                                  // im=+0 keeps +pi convention
}

__device__ __forceinline__ float fast_tanh(float z) {
  const float az = fabsf(z);
  const float e = __builtin_amdgcn_exp2f(-2.8853900817779268f * az);  // exp(-2|z|)
  const float th = fmaf(-2.0f, e * __builtin_amdgcn_rcpf(1.0f + e), 1.0f);
  return copysignf(th, z);
}

// ---------------- Kernel 0: fused setup (softmax + weight transposes) ----------------
__global__ __launch_bounds__(256) void setup_kernel(const float* __restrict__ agg,
                                                    float* __restrict__ wts,
                                                    const float* __restrict__ pw,
                                                    const float* __restrict__ w2,
                                                    float* __restrict__ PWt,
                                                    float* __restrict__ W2t) {
  if (blockIdx.x == 0) {
    __shared__ float red[256];
    const int tid = threadIdx.x;
    float m = -INFINITY;
    for (int i = tid; i < W_; i += 256) m = fmaxf(m, agg[i]);
    red[tid] = m; __syncthreads();
    for (int s = 128; s > 0; s >>= 1) { if (tid < s) red[tid] = fmaxf(red[tid], red[tid+s]); __syncthreads(); }
    const float mx = red[0];
    __syncthreads();
    float sum = 0.f;
    for (int i = tid; i < W_; i += 256) sum += expf(agg[i] - mx);
    red[tid] = sum; __syncthreads();
    for (int s = 128; s > 0; s >>= 1) { if (tid < s) red[tid] += red[tid+s]; __syncthreads(); }
    const float inv = 1.f / red[0];
    for (int i = tid; i < W_; i += 256) wts[i] = expf(agg[i] - mx) * inv;
  } else {
    const int tid = (blockIdx.x - 1) * 256 + threadIdx.x;
    if (tid < MLP_ * FEAT_) {
      const int j = tid / FEAT_, f = tid - j * FEAT_;  // pw[j][f]
      PWt[f * MLP_ + j] = pw[tid];
    }
    if (tid < H2_ * H1_) {
      const int m = tid >> 6, i = tid & 63;            // w2[m][i]
      W2t[i * H2_ + m] = w2[tid];
    }
  }
}

// ---------------- Kernel 1: monolithic fused kernel, ILP-oriented ----------------
// One thread per (b,w). launch_bounds(256,2): VGPR cap 256 == true occupancy (grid
// supplies only ~2 waves/SIMD), so the scheduler can keep 4 independent DFT +
// transcendental chains in flight per channel-pair instead of serializing at VGPR=56.
__global__ __launch_bounds__(256, 2) void tcn_mono(
    const float* __restrict__ x,
    const float* __restrict__ PWt, const float* __restrict__ proj_b,
    const float* __restrict__ w1, const float* __restrict__ b1,
    const float* __restrict__ W2t, const float* __restrict__ b2,
    const float* __restrict__ out_w, const float* __restrict__ out_b,
    const float* __restrict__ wts, float* __restrict__ partials) {
  __shared__ float red[256];
  const int tid = threadIdx.x;
  const int b = blockIdx.y;
  const int w = blockIdx.x * 256 + tid;
  float val = 0.f;
  if (w < W_) {
    float pacc[MLP_];
    #pragma unroll
    for (int j = 0; j < MLP_; j++) pacc[j] = proj_b[j];

    const float* xb = x + (size_t)(b * C_) * T_ + w;
    #pragma unroll 1
    for (int cp = 0; cp < 4; cp++) {
      const int c0 = 2 * cp, c1 = 2 * cp + 1;
      const float* xc0 = xb + c0 * T_;
      const float* xc1 = xb + c1 * T_;
      float win0[K_], win1[K_];
      #pragma unroll
      for (int k = 0; k < K_; k++) win0[k] = xc0[k * 4];
      #pragma unroll
      for (int k = 0; k < K_; k++) win1[k] = xc1[k * 4];

      float ae0[8], bo0[8], ae1[8], bo1[8];
      #pragma unroll
      for (int k = 0; k < 8; k++) {
        ae0[k] = win0[k] + win0[k+8]; bo0[k] = win0[k] - win0[k+8];
        ae1[k] = win1[k] + win1[k+8]; bo1[k] = win1[k] - win1[k+8];
      }

      // ---- n = 0 and n = 8: im == +0 exactly -> cheap mag/phase ----
      {
        const float r00 = ((ae0[0]+ae0[1])+(ae0[2]+ae0[3]))+((ae0[4]+ae0[5])+(ae0[6]+ae0[7]));
        const float r01 = ((ae1[0]+ae1[1])+(ae1[2]+ae1[3]))+((ae1[4]+ae1[5])+(ae1[6]+ae1[7]));
        const float r80 = ((ae0[0]-ae0[1])+(ae0[2]-ae0[3]))+((ae0[4]-ae0[5])+(ae0[6]-ae0[7]));
        const float r81 = ((ae1[0]-ae1[1])+(ae1[2]-ae1[3]))+((ae1[4]-ae1[5])+(ae1[6]-ae1[7]));
        const float mag00 = fast_log1p(fabsf(r00));
        const float mag01 = fast_log1p(fabsf(r01));
        const float mag80 = fast_log1p(fabsf(r80));
        const float mag81 = fast_log1p(fabsf(r81));
        // numpy: angle(re + 0j) = pi if signbit(re) else 0  -> ph = signbit
        const float ph00 = (__float_as_uint(r00) >> 31) ? 1.f : 0.f;
        const float ph01 = (__float_as_uint(r01) >> 31) ? 1.f : 0.f;
        const float ph80 = (__float_as_uint(r80) >> 31) ? 1.f : 0.f;
        const float ph81 = (__float_as_uint(r81) >> 31) ? 1.f : 0.f;
        const float* rm00 = PWt + (size_t)((c0 * NF_ + 0) * 2) * MLP_;
        const float* rm80 = PWt + (size_t)((c0 * NF_ + 8) * 2) * MLP_;
        const float* rm01 = PWt + (size_t)((c1 * NF_ + 0) * 2) * MLP_;
        const float* rm81 = PWt + (size_t)((c1 * NF_ + 8) * 2) * MLP_;
        #pragma unroll
        for (int j = 0; j < MLP_; j++) {
          pacc[j] = fmaf(mag00, rm00[j], fmaf(ph00, rm00[MLP_ + j], pacc[j]));
          pacc[j] = fmaf(mag01, rm01[j], fmaf(ph01, rm01[MLP_ + j], pacc[j]));
          pacc[j] = fmaf(mag80, rm80[j], fmaf(ph80, rm80[MLP_ + j], pacc[j]));
          pacc[j] = fmaf(mag81, rm81[j], fmaf(ph81, rm81[MLP_ + j], pacc[j]));
        }
      }

      // ---- n = 1..7: full twiddles, 4 independent chains (re/im x 2 channels) ----
      #pragma unroll
      for (int n = 1; n < 8; n++) {
        float re0 = 0.f, im0 = 0.f, re1 = 0.f, im1 = 0.f;
        #pragma unroll
        for (int k = 0; k < 8; k++) {
          const int t = (n * k) & 15;
          const float cv = COS16[t], sv = -SIN16F[t];
          const float v0 = (n & 1) ? bo0[k] : ae0[k];
          const float v1 = (n & 1) ? bo1[k] : ae1[k];
          re0 = fmaf(v0, cv, re0); im0 = fmaf(v0, sv, im0);
          re1 = fmaf(v1, cv, re1); im1 = fmaf(v1, sv, im1);
        }
        const float s0   = __builtin_amdgcn_sqrtf(fmaf(re0, re0, im0 * im0));
        const float s1   = __builtin_amdgcn_sqrtf(fmaf(re1, re1, im1 * im1));
        const float mag0 = fast_log1p(s0);
        const float mag1 = fast_log1p(s1);
        const float ph0  = atan2pi_fast(im0, re0);
        const float ph1  = atan2pi_fast(im1, re1);

        const float* rm0 = PWt + (size_t)((c0 * NF_ + n) * 2) * MLP_;  // uniform -> s_load
        const float* rm1 = PWt + (size_t)((c1 * NF_ + n) * 2) * MLP_;
        #pragma unroll
        for (int j = 0; j < MLP_; j++) {
          pacc[j] = fmaf(mag0, rm0[j], fmaf(ph0, rm0[MLP_ + j], pacc[j]));
          pacc[j] = fmaf(mag1, rm1[j], fmaf(ph1, rm1[MLP_ + j], pacc[j]));
        }
      }
    }

    float p[MLP_];
    #pragma unroll
    for (int j = 0; j < MLP_; j++) p[j] = fast_tanh(pacc[j]) * PI_F;

    // ---- MLP tail: weights via wave-uniform scalar loads (proven fastest in R2) ----
    float h2a[H2_];
    #pragma unroll
    for (int m = 0; m < H2_; m++) h2a[m] = b2[m];
    #pragma unroll 8
    for (int i = 0; i < H1_; i++) {
      const float* r1 = w1 + i * MLP_;
      float acc = b1[i];
      #pragma unroll
      for (int j = 0; j < MLP_; j++) acc = fmaf(p[j], r1[j], acc);
      const float h1v = fmaxf(acc, 0.f);
      const float* r2 = W2t + i * H2_;
      #pragma unroll
      for (int m = 0; m < H2_; m++) h2a[m] = fmaf(h1v, r2[m], h2a[m]);
    }
    float o = out_b[0];
    #pragma unroll
    for (int m = 0; m < H2_; m++) o = fmaf(fmaxf(h2a[m], 0.f), out_w[m], o);
    val = o * wts[w];
  }

  // deterministic block reduction
  red[tid] = val; __syncthreads();
  for (int s = 128; s > 0; s >>= 1) { if (tid < s) red[tid] += red[tid+s]; __syncthreads(); }
  if (tid == 0) partials[b * NWCH_ + blockIdx.x] = red[0];
}

// ---------------- finalize ----------------
__global__ void finalize_kernel(const float* __restrict__ partials, float* __restrict__ out) {
  const int b = threadIdx.x;
  if (b < B_) {
    float s = 0.f;
    #pragma unroll
    for (int c = 0; c < NWCH_; c++) s += partials[b * NWCH_ + c];
    out[b] = s;
  }
}

extern "C" void kernel_launch(void* const* d_in, const int* in_sizes, int n_in,
                              void* d_out, int out_size, void* d_ws, size_t ws_size,
                              hipStream_t stream) {
  const float* x      = (const float*)d_in[0];
  const float* proj_w = (const float*)d_in[1];
  const float* proj_b = (const float*)d_in[2];
  const float* w1     = (const float*)d_in[3];
  const float* b1     = (const float*)d_in[4];
  const float* w2     = (const float*)d_in[5];
  const float* b2     = (const float*)d_in[6];
  const float* out_w  = (const float*)d_in[7];
  const float* out_b  = (const float*)d_in[8];
  const float* agg_w  = (const float*)d_in[9];

  float* wts      = (float*)d_ws;                    // W_ floats (2048 slot)
  float* partials = (float*)d_ws + 2048;             // B_*NWCH_ floats
  float* PWt      = (float*)d_ws + 4096;             // FEAT_*MLP_ = 2304 floats
  float* W2t      = (float*)d_ws + 4096 + 2304;      // H1_*H2_ = 2048 floats

  setup_kernel<<<10, 256, 0, stream>>>(agg_w, wts, proj_w, w2, PWt, W2t);
  tcn_mono<<<dim3(NWCH_, B_), 256, 0, stream>>>(x, PWt, proj_b, w1, b1, W2t, b2,
                                                out_w, out_b, wts, partials);
  finalize_kernel<<<1, 64, 0, stream>>>(partials, (float*)d_out);
}

// Round 8
// 59.789 us; speedup vs baseline: 1.1572x; 1.1572x over previous
//
#include <hip/hip_runtime.h>
#include <math.h>

// Problem constants (from reference)
#define B_    64
#define C_    8
#define T_    2048
#define K_    16
#define NF_   9
#define FEAT_ 144   // C_*NF_*2
#define MLP_  16
#define H1_   64
#define H2_   32
#define EFF_  60
#define W_    1988  // T_-EFF_
#define NCHK_ 32    // w-chunks of 64
#define PI_F  3.14159265358979323846f
// LDS padded strides (floats) -- chosen so the 4 sub-groups' b128 reads hit
// disjoint bank quads every instruction (mod-32 analysis in journal):
#define SPW   36    // PWl row-pair stride: base banks {0,8,16,24}+c
#define S1    20    // W1p row stride:      base banks {0,20,8,28}
#define S2    36    // W2p row stride:      base banks {0,4,8,12}+c

// Twiddles: angle(t) = 2*pi*t/16; f[n] = sum win[k]*exp(-i*2*pi*n*k/16)
constexpr float COS16[16] = {
   1.0f,  0.92387953251128674f,  0.70710678118654752f,  0.38268343236508977f,
   0.0f, -0.38268343236508977f, -0.70710678118654752f, -0.92387953251128674f,
  -1.0f, -0.92387953251128674f, -0.70710678118654752f, -0.38268343236508977f,
   0.0f,  0.38268343236508977f,  0.70710678118654752f,  0.92387953251128674f };
constexpr float SIN16F[16] = {
   0.0f,  0.38268343236508977f,  0.70710678118654752f,  0.92387953251128674f,
   1.0f,  0.92387953251128674f,  0.70710678118654752f,  0.38268343236508977f,
   0.0f, -0.38268343236508977f, -0.70710678118654752f, -0.92387953251128674f,
  -1.0f, -0.92387953251128674f, -0.70710678118654752f, -0.38268343236508977f };

// ---- fast device math (hw transcendentals) ----
__device__ __forceinline__ float fast_log1p(float s) {
  return __builtin_amdgcn_logf(1.0f + s) * 0.69314718055994531f;
}

__device__ __forceinline__ float atanpi_poly(float r) {
  const float s2 = r * r;
  float p = -0.0037310f;
  p = fmaf(p, s2,  0.0167600f);
  p = fmaf(p, s2, -0.0370617f);
  p = fmaf(p, s2,  0.0616068f);
  p = fmaf(p, s2, -0.10587734f);
  p = fmaf(p, s2,  0.31830265f);
  return r * p;
}

__device__ __forceinline__ float atan2pi_fast(float im, float re) {
  const float ax = fabsf(re), ay = fabsf(im);
  const float mx = fmaxf(ax, ay), mn = fminf(ax, ay);
  const float r = mn * __builtin_amdgcn_rcpf(fmaxf(mx, 1e-37f));
  float t = atanpi_poly(r);
  t = (ay > ax) ? 0.5f - t : t;
  t = (__float_as_uint(re) & 0x80000000u) ? 1.0f - t : t;  // signbit(re), handles -0
  return copysignf(t, im);                                  // im=+0 keeps +pi convention
}

__device__ __forceinline__ float fast_tanh(float z) {
  const float az = fabsf(z);
  const float e = __builtin_amdgcn_exp2f(-2.8853900817779268f * az);  // exp(-2|z|)
  const float th = fmaf(-2.0f, e * __builtin_amdgcn_rcpf(1.0f + e), 1.0f);
  return copysignf(th, z);
}

// ---------------- Kernel 0: fused setup (softmax + weight transposes) ----------------
__global__ __launch_bounds__(256) void setup_kernel(const float* __restrict__ agg,
                                                    float* __restrict__ wts,
                                                    const float* __restrict__ pw,
                                                    const float* __restrict__ w2,
                                                    float* __restrict__ PWt,
                                                    float* __restrict__ W2t) {
  if (blockIdx.x == 0) {
    __shared__ float red[256];
    const int tid = threadIdx.x;
    float m = -INFINITY;
    for (int i = tid; i < W_; i += 256) m = fmaxf(m, agg[i]);
    red[tid] = m; __syncthreads();
    for (int s = 128; s > 0; s >>= 1) { if (tid < s) red[tid] = fmaxf(red[tid], red[tid+s]); __syncthreads(); }
    const float mx = red[0];
    __syncthreads();
    float sum = 0.f;
    for (int i = tid; i < W_; i += 256) sum += expf(agg[i] - mx);
    red[tid] = sum; __syncthreads();
    for (int s = 128; s > 0; s >>= 1) { if (tid < s) red[tid] += red[tid+s]; __syncthreads(); }
    const float inv = 1.f / red[0];
    for (int i = tid; i < W_; i += 256) wts[i] = expf(agg[i] - mx) * inv;
  } else {
    const int tid = (blockIdx.x - 1) * 256 + threadIdx.x;
    if (tid < MLP_ * FEAT_) {
      const int j = tid / FEAT_, f = tid - j * FEAT_;  // pw[j][f]
      PWt[f * MLP_ + j] = pw[tid];                     // [144][16], pairs (mag,ph) contiguous
    }
    if (tid < H2_ * H1_) {
      const int m = tid >> 6, i = tid & 63;            // w2[m][i]
      W2t[i * H2_ + m] = w2[tid];
    }
  }
}

// ---------------- Kernel 1: monolithic, 4 sub-lanes per w, shuffle combines ----------------
// lane = (sub<<4)|wloc; each sub handles channels {2sub, 2sub+1} and MLP rows i≡sub (mod 4).
// Combines via __shfl_xor (no barriers in body); weights in LDS with bank-disjoint strides.
__global__ __launch_bounds__(256) void tcn_fused(
    const float* __restrict__ x,
    const float* __restrict__ PWt, const float* __restrict__ proj_b,
    const float* __restrict__ w1, const float* __restrict__ b1,
    const float* __restrict__ W2t, const float* __restrict__ b2,
    const float* __restrict__ out_w, const float* __restrict__ out_b,
    const float* __restrict__ wts, float* __restrict__ partials) {
  __shared__ __align__(16) float PWl[72 * SPW];   // row-pair r=c*9+n: [mag16|ph16] @ r*SPW
  __shared__ __align__(16) float W1p[H1_ * S1];
  __shared__ __align__(16) float W2p[H1_ * S2];
  __shared__ float B1s[H1_];

  const int tid = threadIdx.x;
  for (int idx = tid; idx < 72 * 32; idx += 256) { const int r = idx >> 5, j = idx & 31; PWl[r * SPW + j] = PWt[idx]; }
  for (int idx = tid; idx < H1_ * MLP_; idx += 256) { const int i = idx >> 4, j = idx & 15; W1p[i * S1 + j] = w1[idx]; }
  for (int idx = tid; idx < H1_ * H2_; idx += 256) { const int i = idx >> 5, m = idx & 31; W2p[i * S2 + m] = W2t[idx]; }
  if (tid < H1_) B1s[tid] = b1[tid];
  __syncthreads();   // the only barrier in the body

  const int lane = tid & 63;
  const int wave = tid >> 6;
  const int wloc = lane & 15;
  const int sub  = lane >> 4;
  const int b     = blockIdx.y;
  const int chunk = blockIdx.x;
  const int w  = chunk * 64 + wave * 16 + wloc;
  const int wl = (w < W_) ? w : (W_ - 1);   // clamp loads; mask at the end

  // ---- DFT + feature + proj partial for channels 2sub, 2sub+1 ----
  float pacc[MLP_];
  #pragma unroll
  for (int j = 0; j < MLP_; j++) pacc[j] = 0.f;

  #pragma unroll
  for (int cc = 0; cc < 2; cc++) {
    const int c = sub * 2 + cc;
    const float* xc = x + ((size_t)b * C_ + c) * T_ + wl;
    float win[K_];
    #pragma unroll
    for (int k = 0; k < K_; k++) win[k] = xc[k * 4];
    float ae[8], bo[8];
    #pragma unroll
    for (int k = 0; k < 8; k++) { ae[k] = win[k] + win[k+8]; bo[k] = win[k] - win[k+8]; }

    #pragma unroll
    for (int n = 0; n < NF_; n++) {
      float re = 0.f, im = 0.f;
      #pragma unroll
      for (int k = 0; k < 8; k++) {
        const float v = (n & 1) ? bo[k] : ae[k];
        const int t = (n * k) & 15;
        re = fmaf(v,  COS16[t],  re);
        im = fmaf(v, -SIN16F[t], im);   // im stays +0.0 exactly for n=0,8
      }
      const float s   = __builtin_amdgcn_sqrtf(fmaf(re, re, im * im));
      const float mag = fast_log1p(s);
      const float ph  = atan2pi_fast(im, re);
      const float4* rmv = reinterpret_cast<const float4*>(&PWl[(c * NF_ + n) * SPW]);
      #pragma unroll
      for (int q = 0; q < 4; q++) {
        const float4 a  = rmv[q];       // mag weights
        const float4 bb = rmv[q + 4];   // ph weights
        pacc[4*q+0] = fmaf(mag, a.x, fmaf(ph, bb.x, pacc[4*q+0]));
        pacc[4*q+1] = fmaf(mag, a.y, fmaf(ph, bb.y, pacc[4*q+1]));
        pacc[4*q+2] = fmaf(mag, a.z, fmaf(ph, bb.z, pacc[4*q+2]));
        pacc[4*q+3] = fmaf(mag, a.w, fmaf(ph, bb.w, pacc[4*q+3]));
      }
    }
  }

  // ---- combine pacc across subs (butterfly over lane bits 4,5; all lanes identical) ----
  #pragma unroll
  for (int j = 0; j < MLP_; j++) {
    pacc[j] += __shfl_xor(pacc[j], 16, 64);
    pacc[j] += __shfl_xor(pacc[j], 32, 64);
  }
  float p[MLP_];
  #pragma unroll
  for (int j = 0; j < MLP_; j++) p[j] = fast_tanh(pacc[j] + proj_b[j]) * PI_F;

  // ---- MLP tail: 16 rows per sub (i = sub + 4*ii), partial h2a ----
  float h2a[H2_];
  #pragma unroll
  for (int m = 0; m < H2_; m++) h2a[m] = 0.f;
  #pragma unroll 4
  for (int ii = 0; ii < 16; ii++) {
    const int i = sub + ii * 4;
    const float4* r1 = reinterpret_cast<const float4*>(&W1p[i * S1]);
    float acc = B1s[i];
    #pragma unroll
    for (int q = 0; q < 4; q++) {
      const float4 a = r1[q];
      acc = fmaf(p[4*q+0], a.x, acc);
      acc = fmaf(p[4*q+1], a.y, acc);
      acc = fmaf(p[4*q+2], a.z, acc);
      acc = fmaf(p[4*q+3], a.w, acc);
    }
    const float h1v = fmaxf(acc, 0.f);
    const float4* r2 = reinterpret_cast<const float4*>(&W2p[i * S2]);
    #pragma unroll
    for (int q = 0; q < 8; q++) {
      const float4 a = r2[q];
      h2a[4*q+0] = fmaf(h1v, a.x, h2a[4*q+0]);
      h2a[4*q+1] = fmaf(h1v, a.y, h2a[4*q+1]);
      h2a[4*q+2] = fmaf(h1v, a.z, h2a[4*q+2]);
      h2a[4*q+3] = fmaf(h1v, a.w, h2a[4*q+3]);
    }
  }
  // ---- combine h2a across subs ----
  #pragma unroll
  for (int m = 0; m < H2_; m++) {
    h2a[m] += __shfl_xor(h2a[m], 16, 64);
    h2a[m] += __shfl_xor(h2a[m], 32, 64);
  }

  // ---- head (all lanes; only sub0 contributes) + weighted wave reduction ----
  float o = out_b[0];
  #pragma unroll
  for (int m = 0; m < H2_; m++) o = fmaf(fmaxf(h2a[m] + b2[m], 0.f), out_w[m], o);
  float val = (sub == 0 && w < W_) ? o * wts[wl] : 0.f;
  #pragma unroll
  for (int s = 1; s < 64; s <<= 1) val += __shfl_xor(val, s, 64);
  if (lane == 0) partials[(b * NCHK_ + chunk) * 4 + wave] = val;
}

// ---------------- finalize: fixed-order sum of 128 partials per b ----------------
__global__ void finalize_kernel(const float* __restrict__ partials, float* __restrict__ out) {
  const int b = threadIdx.x;
  if (b < B_) {
    float s = 0.f;
    #pragma unroll 4
    for (int c = 0; c < NCHK_ * 4; c++) s += partials[b * NCHK_ * 4 + c];
    out[b] = s;
  }
}

extern "C" void kernel_launch(void* const* d_in, const int* in_sizes, int n_in,
                              void* d_out, int out_size, void* d_ws, size_t ws_size,
                              hipStream_t stream) {
  const float* x      = (const float*)d_in[0];
  const float* proj_w = (const float*)d_in[1];
  const float* proj_b = (const float*)d_in[2];
  const float* w1     = (const float*)d_in[3];
  const float* b1     = (const float*)d_in[4];
  const float* w2     = (const float*)d_in[5];
  const float* b2     = (const float*)d_in[6];
  const float* out_w  = (const float*)d_in[7];
  const float* out_b  = (const float*)d_in[8];
  const float* agg_w  = (const float*)d_in[9];

  float* wts      = (float*)d_ws;                    // 2048 floats
  float* PWt      = (float*)d_ws + 2048;             // FEAT_*MLP_ = 2304 floats
  float* W2t      = (float*)d_ws + 2048 + 2304;      // H1_*H2_ = 2048 floats (ends 6400)
  float* partials = (float*)d_ws + 8192;             // B_*NCHK_*4 = 8192 floats

  setup_kernel<<<10, 256, 0, stream>>>(agg_w, wts, proj_w, w2, PWt, W2t);
  tcn_fused<<<dim3(NCHK_, B_), 256, 0, stream>>>(x, PWt, proj_b, w1, b1, W2t, b2,
                                                 out_w, out_b, wts, partials);
  finalize_kernel<<<1, 64, 0, stream>>>(partials, (float*)d_out);
}